// Round 12
// baseline (226.269 us; speedup 1.0000x reference)
//
#include <hip/hip_runtime.h>
#include <cstddef>

#define NSIDE_ 128
#define NLAT_  511
#define NLON_  512
#define LMAX_  511
#define MMAX_  257
#define NPIX_  196608
#define TWO_PI_ 6.28318530717958647692f

#define X2ELEMS_  16809856u   // 511*257*2*64 ushorts (X bf16, [k][m][ri][b])
#define X2TELEMS_ 16842752u   // 257*128*512 ushorts (x2T bf16, [m][rb][l])

typedef __attribute__((ext_vector_type(8))) short bf16x8;
typedef __attribute__((ext_vector_type(4))) float f32x4;

static __device__ __forceinline__ unsigned short f2bf(float f) {
    union { float f; unsigned int u; } v; v.f = f;
    unsigned int r = v.u + 0x7FFFu + ((v.u >> 16) & 1u);   // RNE
    return (unsigned short)(r >> 16);
}

static __device__ __forceinline__ unsigned int cvtpk(float lo, float hi) {
    unsigned int d;
    asm("v_cvt_pk_bf16_f32 %0, %1, %2" : "=v"(d) : "v"(lo), "v"(hi));
    return d;
}

static __device__ __forceinline__ bf16x8 ld_pair(const unsigned int* p) {
    union { struct { uint2 a, b; } s; bf16x8 v; } t;
    t.s.a = *(const uint2*)p;
    t.s.b = *(const uint2*)(p + 2);
    return t.v;
}

// ---------------------------------------------------------------------------
// K0: pack x[b][l][m][ri] (f32) -> x2T[m][rb][l] (bf16), rb = ri*64+b,
// l zero-padded to 512.  (r11 verbatim)
// ---------------------------------------------------------------------------
__global__ __launch_bounds__(256) void pack_x_k(
    const float* __restrict__ x, unsigned short* __restrict__ x2T)
{
    __shared__ unsigned short lds[32][520];
    int b   = blockIdx.x;
    int l0  = blockIdx.y * 32;
    int tid = threadIdx.x;

    const float* src = x + ((size_t)b * LMAX_ + l0) * (2 * MMAX_);
    for (int li = 0; li < 32; ++li) {
        bool valid = (l0 + li) < LMAX_;
        for (int m2 = tid; m2 < 2 * MMAX_; m2 += 256) {
            float f = valid ? src[(size_t)li * (2 * MMAX_) + m2] : 0.f;
            lds[li][m2] = f2bf(f);
        }
    }
    __syncthreads();

    for (int m2 = tid; m2 < 2 * MMAX_; m2 += 256) {
        int m  = m2 >> 1;
        int rb = (m2 & 1) * 64 + b;
        unsigned short* dst = x2T + ((size_t)m * 128 + rb) * 512 + l0;
#pragma unroll
        for (int g = 0; g < 4; ++g) {
            unsigned int w0 = (unsigned int)lds[g*8+0][m2] | ((unsigned int)lds[g*8+1][m2] << 16);
            unsigned int w1 = (unsigned int)lds[g*8+2][m2] | ((unsigned int)lds[g*8+3][m2] << 16);
            unsigned int w2 = (unsigned int)lds[g*8+4][m2] | ((unsigned int)lds[g*8+5][m2] << 16);
            unsigned int w3 = (unsigned int)lds[g*8+6][m2] | ((unsigned int)lds[g*8+7][m2] << 16);
            *(uint4*)(dst + g * 8) = make_uint4(w0, w1, w2, w3);
        }
    }
}

// ---------------------------------------------------------------------------
// K1: Legendre MFMA. r11 structure; delta = OCCUPANCY: B-fragment double
// buffer dropped (x2T is L2-resident, ~200cyc — loaded in-step), freeing
// ~32 VGPR, and __launch_bounds__(256,4): 4 blocks/CU -> whole grid
// (1028 blocks) co-resident, 16 waves/CU to hide the pct HBM latency.
// ---------------------------------------------------------------------------
__global__ __launch_bounds__(256, 4) void legendre12_k(
    const unsigned short* __restrict__ x2T,
    const float* __restrict__ pct,
    unsigned short* __restrict__ X2)
{
    __shared__ __align__(16) unsigned int Apk[2][128 * 18];

    int bid = blockIdx.x;
    int xcd = bid & 7, n = bid >> 3;
    int kt = n & 3, mi = n >> 2;
    int m = mi * 8 + xcd;
    if (m >= MMAX_) return;

    int k0  = kt * 128;
    int tid = threadIdx.x;
    int lane = tid & 63, w = tid >> 6;
    int wk = (w >> 1) * 64, wrb = (w & 1) * 64;
    int r = lane & 15, g = lane >> 4;

    const float* pctm = pct + (size_t)m * (LMAX_ * NLAT_);
    const unsigned short* x2m = x2T + (size_t)m * (128 * 512);

    int kc = tid & 15;
    int lp = tid >> 4;
    int o7 = (k0 + kc + 112 <= NLAT_ - 1) ? 112 : (NLAT_ - 1 - (k0 + kc));

    f32x4 acc[4][4];
#pragma unroll
    for (int a = 0; a < 4; ++a)
#pragma unroll
        for (int c = 0; c < 4; ++c) acc[a][c] = (f32x4){0.f, 0.f, 0.f, 0.f};

    float e0[8], e1[8];
    bf16x8 Bfc[4];

    auto load_pct = [&](int step) {
        int la = step * 32 + 2 * lp, lb = la + 1;
        if (lb > LMAX_ - 1) lb = LMAX_ - 1;        // l=511 pad (B zero there)
        const float* pa = pctm + (size_t)la * NLAT_ + k0 + kc;
        const float* pb = pctm + (size_t)lb * NLAT_ + k0 + kc;
#pragma unroll
        for (int i = 0; i < 7; ++i) { e0[i] = pa[16 * i]; e1[i] = pb[16 * i]; }
        e0[7] = pa[o7]; e1[7] = pb[o7];
    };

    load_pct(0);                                   // prologue: step-0 pct

#pragma unroll 2
    for (int s = 0; s < 16; ++s) {
        const int bsel = s & 1;
        unsigned int* wp = &Apk[bsel][0];
#pragma unroll
        for (int i = 0; i < 8; ++i) {
            unsigned int dwv = cvtpk(e0[i], e1[i]);
            int kk = kc + 16 * i;
            wp[kk * 18 + (lp ^ ((i & 3) << 2))] = dwv;
        }
        __syncthreads();

        // in-step B load (L2-resident x2T slab) + depth-1 pct prefetch
        {
            int lbase = s * 32 + g * 8;
#pragma unroll
            for (int rs = 0; rs < 4; ++rs)
                Bfc[rs] = *(const bf16x8*)(x2m + (size_t)(wrb + rs * 16 + r) * 512 + lbase);
        }
        if (s < 15) load_pct(s + 1);

        const unsigned int* rp = &Apk[bsel][0];
        bf16x8 Af[4];
#pragma unroll
        for (int ks = 0; ks < 4; ++ks) {
            int row = wk + ks * 16 + r;
            Af[ks] = ld_pair(rp + row * 18 + ((g * 4) ^ ((ks & 3) << 2)));
        }
#pragma unroll
        for (int ks = 0; ks < 4; ++ks)
#pragma unroll
            for (int rs = 0; rs < 4; ++rs)
                acc[ks][rs] = __builtin_amdgcn_mfma_f32_16x16x32_bf16(
                    Af[ks], Bfc[rs], acc[ks][rs], 0, 0, 0);
    }

    float wgt = (m == 0) ? 1.f : 2.f;
#pragma unroll
    for (int ks = 0; ks < 4; ++ks) {
#pragma unroll
        for (int rs = 0; rs < 4; ++rs) {
            int rb = wrb + rs * 16 + r;
            int ri = rb >> 6, b = rb & 63;
#pragma unroll
            for (int i = 0; i < 4; ++i) {
                int k = k0 + wk + ks * 16 + g * 4 + i;
                if (k < NLAT_)
                    X2[(((size_t)k * MMAX_ + m) * 2 + ri) * 64 + b] =
                        f2bf(acc[ks][rs][i] * wgt);
            }
        }
    }
}

// ---------------------------------------------------------------------------
// K2: synthesis MFMA (r11 verbatim): bf16 X2 input, 1 barrier/step, dbuf,
// prefetch, trig recurrence on VALU overlapping MFMA.
// ---------------------------------------------------------------------------
__global__ __launch_bounds__(256, 3) void synth5_k(
    const unsigned short* __restrict__ X2,
    float* __restrict__ out)
{
    __shared__ __align__(16) unsigned int Adw[2][256 * 18];
    __shared__ __align__(16) unsigned int Bdw[2][64 * 18];

    int k  = blockIdx.x;
    int jh = blockIdx.y;

    int nphi, start; float off;
    if (k < NSIDE_ - 1) {
        nphi  = 4 * (k + 1);
        start = 2 * k * (k + 1);
        off   = 0.5f;
    } else if (k <= 3 * NSIDE_ - 1) {
        nphi  = 4 * NSIDE_;
        start = 2 * (NSIDE_ - 1) * NSIDE_ + (k - (NSIDE_ - 1)) * 4 * NSIDE_;
        off   = (((k - (NSIDE_ - 1)) & 1) == 0) ? 0.5f : 0.f;
    } else {
        int t = NLAT_ - k;
        nphi  = 4 * t;
        start = NPIX_ - 2 * t * (t + 1);
        off   = 0.5f;
    }
    int jblk = jh * 256;
    if (jblk >= nphi) return;

    int tid  = threadIdx.x;
    int lane = tid & 63, w = tid >> 6;
    int r = lane & 15, g = lane >> 4;

    float theta = TWO_PI_ * ((float)(jblk + tid) + off) / (float)nphi;
    float dc, ds;
    sincosf(theta, &ds, &dc);
    float cs = 1.f, sn = 0.f;

    int bb = tid & 63, kq = tid >> 6;
    const unsigned short* Xk = X2 + (size_t)k * (MMAX_ * 2 * 64) + bb;

    int swzA = ((tid >> 4) & 3) << 2;
    int swzB = ((bb  >> 4) & 3) << 2;

    unsigned short hv[8];
#pragma unroll
    for (int i = 0; i < 8; ++i) {
        int kap = kq * 8 + i;
        hv[i] = Xk[((size_t)(kap >> 1) * 2 + (kap & 1)) * 64];
    }
    unsigned int adw[16];
#pragma unroll
    for (int mi2 = 0; mi2 < 16; ++mi2) {
        adw[mi2] = cvtpk(cs, -sn);
        float cn = fmaf(cs, dc, -(sn * ds));
        float s2 = fmaf(sn, dc,  cs * ds);
        cs = cn; sn = s2;
    }
    unsigned int bdw[4];
#pragma unroll
    for (int q = 0; q < 4; ++q)
        bdw[q] = (unsigned int)hv[2 * q] | ((unsigned int)hv[2 * q + 1] << 16);

    bool wact = (jblk + w * 64) < nphi;

    f32x4 acc[4][4];
#pragma unroll
    for (int a = 0; a < 4; ++a)
#pragma unroll
        for (int c = 0; c < 4; ++c) acc[a][c] = (f32x4){0.f, 0.f, 0.f, 0.f};

#pragma unroll 2
    for (int s = 0; s < 17; ++s) {
        const int bsel = s & 1;
        {
            unsigned int* ap = &Adw[bsel][tid * 18];
#pragma unroll
            for (int q = 0; q < 8; ++q)
                *(uint2*)(ap + ((2 * q) ^ swzA)) = make_uint2(adw[2 * q], adw[2 * q + 1]);
            unsigned int* bp = &Bdw[bsel][bb * 18];
            int cb = (kq * 4) ^ swzB;
            *(uint2*)(bp + cb)     = make_uint2(bdw[0], bdw[1]);
            *(uint2*)(bp + cb + 2) = make_uint2(bdw[2], bdw[3]);
        }
        __syncthreads();

        if (s < 16) {
            int kap0 = (s + 1) * 32 + kq * 8;
#pragma unroll
            for (int i = 0; i < 8; ++i) {
                int kap = kap0 + i;
                int mm  = kap >> 1;
                hv[i] = (mm < MMAX_) ? Xk[((size_t)mm * 2 + (kap & 1)) * 64]
                                     : (unsigned short)0;
            }
        }
        if (s < 16) {
#pragma unroll
            for (int mi2 = 0; mi2 < 16; ++mi2) {
                adw[mi2] = cvtpk(cs, -sn);
                float cn = fmaf(cs, dc, -(sn * ds));
                float s2 = fmaf(sn, dc,  cs * ds);
                cs = cn; sn = s2;
            }
        }

        if (wact) {
            const unsigned int* arp = &Adw[bsel][0];
            const unsigned int* brp = &Bdw[bsel][0];
            bf16x8 Af[4], Bf[4];
#pragma unroll
            for (int ks = 0; ks < 4; ++ks) {
                int row = w * 64 + ks * 16 + r;
                Af[ks] = ld_pair(arp + row * 18 + ((g * 4) ^ ((ks & 3) << 2)));
            }
#pragma unroll
            for (int bs = 0; bs < 4; ++bs) {
                int row = bs * 16 + r;
                Bf[bs] = ld_pair(brp + row * 18 + ((g * 4) ^ ((bs & 3) << 2)));
            }
#pragma unroll
            for (int ks = 0; ks < 4; ++ks)
#pragma unroll
                for (int bs = 0; bs < 4; ++bs)
                    acc[ks][bs] = __builtin_amdgcn_mfma_f32_16x16x32_bf16(
                        Af[ks], Bf[bs], acc[ks][bs], 0, 0, 0);
        }

        if (s < 16) {
#pragma unroll
            for (int q = 0; q < 4; ++q)
                bdw[q] = (unsigned int)hv[2 * q] | ((unsigned int)hv[2 * q + 1] << 16);
        }
    }

    if (wact) {
#pragma unroll
        for (int ks = 0; ks < 4; ++ks)
#pragma unroll
            for (int bs = 0; bs < 4; ++bs) {
                int b = bs * 16 + r;
#pragma unroll
                for (int i = 0; i < 4; ++i) {
                    int j = jblk + w * 64 + ks * 16 + g * 4 + i;
                    if (j < nphi)
                        out[(size_t)b * NPIX_ + start + j] = acc[ks][bs][i];
                }
            }
    }
}

// ---------------------------------------------------------------------------
// Fallbacks (small ws): round-2 proven kernels (f32 X in d_ws).
// ---------------------------------------------------------------------------
__global__ __launch_bounds__(256) void legendre_k(
    const float* __restrict__ x,
    const float* __restrict__ pct,
    float* __restrict__ X)
{
    int k  = blockIdx.x * 256 + threadIdx.x;
    int m  = blockIdx.y;
    int bh = blockIdx.z;
    bool active = (k < NLAT_);
    if (!active) k = NLAT_ - 1;

    float accR[32], accI[32];
#pragma unroll
    for (int i = 0; i < 32; ++i) { accR[i] = 0.f; accI[i] = 0.f; }

    const float* pcol  = pct + (size_t)m * LMAX_ * NLAT_ + k;
    const float* xbase = x + (size_t)(bh * 32) * LMAX_ * MMAX_ * 2 + (size_t)m * 2;
    const size_t bstride = (size_t)LMAX_ * MMAX_ * 2;

    for (int l = 0; l < LMAX_; ++l) {
        float p = pcol[(size_t)l * NLAT_];
        const float* xl = xbase + (size_t)l * MMAX_ * 2;
#pragma unroll
        for (int bb = 0; bb < 32; ++bb) {
            accR[bb] = fmaf(xl[(size_t)bb * bstride],     p, accR[bb]);
            accI[bb] = fmaf(xl[(size_t)bb * bstride + 1], p, accI[bb]);
        }
    }
    if (active) {
        float wv = (m == 0) ? 1.f : 2.f;
        size_t base = ((size_t)k * MMAX_ + m) * 128 + bh * 32;
#pragma unroll
        for (int bb = 0; bb < 32; ++bb) {
            X[base + bb]      = accR[bb] * wv;
            X[base + 64 + bb] = accI[bb] * wv;
        }
    }
}

__global__ __launch_bounds__(256) void synth2_k(
    const float* __restrict__ X,
    float* __restrict__ out)
{
    int k  = blockIdx.x;
    int j  = blockIdx.y * 256 + threadIdx.x;
    int bh = blockIdx.z;

    int nphi, start; float off;
    if (k < NSIDE_ - 1) {
        nphi  = 4 * (k + 1);
        start = 2 * k * (k + 1);
        off   = 0.5f;
    } else if (k <= 3 * NSIDE_ - 1) {
        nphi  = 4 * NSIDE_;
        start = 2 * (NSIDE_ - 1) * NSIDE_ + (k - (NSIDE_ - 1)) * 4 * NSIDE_;
        off   = (((k - (NSIDE_ - 1)) & 1) == 0) ? 0.5f : 0.f;
    } else {
        int t = NLAT_ - k;
        nphi  = 4 * t;
        start = NPIX_ - 2 * t * (t + 1);
        off   = 0.5f;
    }
    if (blockIdx.y == 1 && nphi <= 256) return;
    bool store_ok = (j < nphi);

    float ang = TWO_PI_ * ((float)j + off) / (float)nphi;
    float dsn, dcs;
    sincosf(ang, &dsn, &dcs);

    const float* Xk = X + (size_t)k * MMAX_ * 128 + bh * 32;

    float acc[32];
#pragma unroll
    for (int i = 0; i < 32; ++i) acc[i] = 0.f;

    float c = 1.f, s = 0.f;
    for (int m = 0; m < MMAX_; ++m) {
        const float* xm = Xk + (size_t)m * 128;
#pragma unroll
        for (int bb = 0; bb < 32; ++bb) {
            acc[bb] = fmaf(c, xm[bb], acc[bb]);
            acc[bb] = fmaf(-s, xm[64 + bb], acc[bb]);
        }
        float cn = fmaf(c, dcs, -(s * dsn));
        float s2 = fmaf(s, dcs,  (c * dsn));
        c = cn; s = s2;
    }

    if (store_ok) {
        float* op = out + (size_t)(bh * 32) * NPIX_ + start + j;
#pragma unroll
        for (int bb = 0; bb < 32; ++bb)
            op[(size_t)bb * NPIX_] = acc[bb];
    }
}

// ---------------------------------------------------------------------------
extern "C" void kernel_launch(void* const* d_in, const int* in_sizes, int n_in,
                              void* d_out, int out_size, void* d_ws, size_t ws_size,
                              hipStream_t stream)
{
    const float* x   = (const float*)d_in[0];
    const float* pct = (const float*)d_in[1];
    // d_in[2]=A, d_in[3]=B, d_in[4]=fidx unused (trig + ring offsets on device)
    float* out = (float*)d_out;

    size_t need = (size_t)X2ELEMS_ * 2 + (size_t)X2TELEMS_ * 2;  // 67.3 MB
    if (ws_size >= need) {
        unsigned short* X2  = (unsigned short*)d_ws;             // 33.6 MB
        unsigned short* x2T = X2 + X2ELEMS_;                     // 33.7 MB
        pack_x_k<<<dim3(64, 16), dim3(256), 0, stream>>>(x, x2T);
        legendre12_k<<<dim3(1056), dim3(256), 0, stream>>>(x2T, pct, X2);
        synth5_k<<<dim3(NLAT_, 2), dim3(256), 0, stream>>>(X2, out);
    } else {
        float* X = (float*)d_ws;
        legendre_k<<<dim3(2, MMAX_, 2), dim3(256), 0, stream>>>(x, pct, X);
        synth2_k<<<dim3(NLAT_, 2, 2), dim3(256), 0, stream>>>(X, out);
    }
}